// Round 2
// baseline (10328.978 us; speedup 1.0000x reference)
//
#include <hip/hip_runtime.h>
#include <math.h>

#define Bq 16
#define Hc 384
#define Tt 2048
#define N2 32
#define LYR 6
#define HFq 1536
#define TWOH 768
#define CHUNK 128
#define NCH (Tt/CHUNK)   // 16

// ---------------- param precompute (fp64 for accuracy) ----------------
__global__ void param_kernel(const float* __restrict__ log_dt,
                             const float* __restrict__ A_re, const float* __restrict__ A_im,
                             const float* __restrict__ C_re, const float* __restrict__ C_im,
                             float* __restrict__ wre, float* __restrict__ wim,
                             float* __restrict__ cdre, float* __restrict__ cdim,
                             float* __restrict__ wSre, float* __restrict__ wSim) {
  int idx = blockIdx.x * blockDim.x + threadIdx.x;
  if (idx >= LYR * Hc * N2) return;
  int hn = idx / N2;  // i*H + h
  double dt = exp((double)log_dt[hn]);
  double are = (double)A_re[idx], aim = (double)A_im[idx];
  double dre = are * dt, dimv = aim * dt;
  double er = exp(dre);
  double wr = er * cos(dimv), wi_ = er * sin(dimv);
  double den = are * are + aim * aim;
  double nr = wr - 1.0, ni = wi_;
  double qr = (nr * are + ni * aim) / den;
  double qi = (ni * are - nr * aim) / den;
  double cr = (double)C_re[idx], ci = (double)C_im[idx];
  cdre[idx] = (float)(2.0 * (cr * qr - ci * qi));   // factor 2 (2*Re) folded in
  cdim[idx] = (float)(2.0 * (cr * qi + ci * qr));
  wre[idx] = (float)wr; wim[idx] = (float)wi_;
  double es = exp(dre * (double)CHUNK);
  wSre[idx] = (float)(es * cos(dimv * (double)CHUNK));
  wSim[idx] = (float)(es * sin(dimv * (double)CHUNK));
}

// ---------------- scan phase 1: chunk-local states ----------------
__global__ __launch_bounds__(256, 1) void scan_local(
    const float* __restrict__ x, const float* __restrict__ mask,
    const float* __restrict__ wre, const float* __restrict__ wim,
    float* __restrict__ states) {
  int tid = blockIdx.x * 256 + threadIdx.x;  // B*H*NCH
  int c = tid & (NCH - 1);
  int h = (tid / NCH) % Hc;
  int b = tid / (NCH * Hc);
  const float* xp = x + ((size_t)(b * Hc + h)) * Tt + c * CHUNK;
  const float* mp = mask + (size_t)b * Tt + c * CHUNK;
  float wr[N2], wi[N2], sr[N2], si[N2];
#pragma unroll
  for (int n = 0; n < N2; n++) {
    wr[n] = wre[h * N2 + n]; wi[n] = wim[h * N2 + n];
    sr[n] = 0.f; si[n] = 0.f;
  }
  for (int t = 0; t < CHUNK; t += 4) {
    float4 xv = *(const float4*)(xp + t);
    float4 mv = *(const float4*)(mp + t);
    float xs[4] = {xv.x * mv.x, xv.y * mv.y, xv.z * mv.z, xv.w * mv.w};
#pragma unroll
    for (int j = 0; j < 4; j++) {
      float u = xs[j];
#pragma unroll
      for (int n = 0; n < N2; n++) {
        float s0 = sr[n];
        sr[n] = fmaf(wr[n], s0, fmaf(-wi[n], si[n], u));
        si[n] = fmaf(wr[n], si[n], wi[n] * s0);
      }
    }
  }
  float* sp = states + (size_t)tid * (2 * N2);
#pragma unroll
  for (int n = 0; n < N2; n++) { sp[2 * n] = sr[n]; sp[2 * n + 1] = si[n]; }
}

// ---------------- scan phase 2: prefix over chunks ----------------
__global__ __launch_bounds__(256, 1) void scan_prefix(
    float* __restrict__ states,
    const float* __restrict__ wSre, const float* __restrict__ wSim) {
  int tid = blockIdx.x * 256 + threadIdx.x;  // B*H
  if (tid >= Bq * Hc) return;
  int h = tid % Hc;
  float wr[N2], wi[N2], cr_[N2], ci_[N2];
#pragma unroll
  for (int n = 0; n < N2; n++) {
    wr[n] = wSre[h * N2 + n]; wi[n] = wSim[h * N2 + n];
    cr_[n] = 0.f; ci_[n] = 0.f;
  }
  float* base = states + (size_t)tid * NCH * 2 * N2;
  for (int c = 0; c < NCH; c++) {
    float* sp = base + c * 2 * N2;
#pragma unroll
    for (int n = 0; n < N2; n++) {
      float lr = sp[2 * n], li = sp[2 * n + 1];
      sp[2 * n] = cr_[n]; sp[2 * n + 1] = ci_[n];  // incoming state for chunk c
      float c0 = cr_[n];
      cr_[n] = fmaf(wr[n], c0, fmaf(-wi[n], ci_[n], lr));
      ci_[n] = fmaf(wr[n], ci_[n], fmaf(wi[n], c0, li));
    }
  }
}

// ---------------- scan phase 3: outputs + D*x + exact GELU ----------------
__global__ __launch_bounds__(256, 1) void scan_out(
    const float* __restrict__ x, const float* __restrict__ mask,
    const float* __restrict__ wre, const float* __restrict__ wim,
    const float* __restrict__ cdre, const float* __restrict__ cdim,
    const float* __restrict__ Dv, const float* __restrict__ states,
    float* __restrict__ y) {
  int tid = blockIdx.x * 256 + threadIdx.x;  // B*H*NCH
  int c = tid & (NCH - 1);
  int h = (tid / NCH) % Hc;
  int b = tid / (NCH * Hc);
  size_t rowoff = ((size_t)(b * Hc + h)) * Tt + (size_t)c * CHUNK;
  const float* xp = x + rowoff;
  const float* mp = mask + (size_t)b * Tt + c * CHUNK;
  float* yp = y + rowoff;
  float wr[N2], wi[N2], cdr[N2], cdi[N2], sr[N2], si[N2];
  const float* sp = states + (size_t)tid * (2 * N2);
#pragma unroll
  for (int n = 0; n < N2; n++) {
    wr[n] = wre[h * N2 + n]; wi[n] = wim[h * N2 + n];
    cdr[n] = cdre[h * N2 + n]; cdi[n] = cdim[h * N2 + n];
    sr[n] = sp[2 * n]; si[n] = sp[2 * n + 1];
  }
  float d = Dv[h];
  for (int t = 0; t < CHUNK; t += 4) {
    float4 xv = *(const float4*)(xp + t);
    float4 mv = *(const float4*)(mp + t);
    float xs[4] = {xv.x * mv.x, xv.y * mv.y, xv.z * mv.z, xv.w * mv.w};
    float ys[4];
#pragma unroll
    for (int j = 0; j < 4; j++) {
      float u = xs[j];
      float acc = 0.f;
#pragma unroll
      for (int n = 0; n < N2; n++) {
        float s0 = sr[n];
        sr[n] = fmaf(wr[n], s0, fmaf(-wi[n], si[n], u));
        si[n] = fmaf(wr[n], si[n], wi[n] * s0);
        acc = fmaf(cdr[n], sr[n], fmaf(-cdi[n], si[n], acc));
      }
      float v = fmaf(d, u, acc);
      ys[j] = 0.5f * v * (1.0f + erff(v * 0.70710678118654752f));
    }
    *(float4*)(yp + t) = make_float4(ys[0], ys[1], ys[2], ys[3]);
  }
}

// ---------------- fp32 GEMM: C[z] = A (M,K) * B[z] (K,T) (+bias, relu, col-mask) ----------------
// per-z strides: B += z*K*Tt, C += z*M*Tt, mask += z*Tt
template <int RELU, int MASKB>
__global__ __launch_bounds__(256) void gemm_kernel(
    const float* __restrict__ A, const float* __restrict__ Bg,
    const float* __restrict__ bias, const float* __restrict__ mask,
    float* __restrict__ Cg, int M, int K) {
  __shared__ float As[8][128];
  __shared__ float Bs[8][128];
  int tid = threadIdx.x;
  int bz = blockIdx.z;
  const float* Bp = Bg + (size_t)bz * K * Tt;
  float* Cp = Cg + (size_t)bz * M * Tt;
  int bm = blockIdx.y * 128, bn = blockIdx.x * 128;
  int am = tid >> 1, ak = (tid & 1) * 4;
  int bk = tid >> 5, bn4 = (tid & 31) * 4;
  float4 mv4 = make_float4(1.f, 1.f, 1.f, 1.f);
  if (MASKB) mv4 = *(const float4*)(mask + (size_t)bz * Tt + bn + bn4);
  int tx = tid & 15, ty = tid >> 4;
  float acc[8][8];
#pragma unroll
  for (int i = 0; i < 8; i++)
#pragma unroll
    for (int j = 0; j < 8; j++) acc[i][j] = 0.f;
  const float* Aptr = A + (size_t)(bm + am) * K + ak;
  const float* Bptr = Bp + (size_t)bk * Tt + bn + bn4;
  for (int k0 = 0; k0 < K; k0 += 8) {
    float4 av = *(const float4*)(Aptr + k0);
    float4 bv = *(const float4*)(Bptr + (size_t)k0 * Tt);
    if (MASKB) { bv.x *= mv4.x; bv.y *= mv4.y; bv.z *= mv4.z; bv.w *= mv4.w; }
    __syncthreads();
    As[ak + 0][am] = av.x; As[ak + 1][am] = av.y;
    As[ak + 2][am] = av.z; As[ak + 3][am] = av.w;
    *(float4*)&Bs[bk][bn4] = bv;
    __syncthreads();
#pragma unroll
    for (int kk = 0; kk < 8; kk++) {
      float a[8], bb[8];
      *(float4*)&a[0] = *(const float4*)&As[kk][ty * 4];
      *(float4*)&a[4] = *(const float4*)&As[kk][64 + ty * 4];
      *(float4*)&bb[0] = *(const float4*)&Bs[kk][tx * 4];
      *(float4*)&bb[4] = *(const float4*)&Bs[kk][64 + tx * 4];
#pragma unroll
      for (int i = 0; i < 8; i++)
#pragma unroll
        for (int j = 0; j < 8; j++) acc[i][j] = fmaf(a[i], bb[j], acc[i][j]);
    }
  }
#pragma unroll
  for (int i = 0; i < 8; i++) {
    int row = bm + ((i < 4) ? (ty * 4 + i) : (64 + ty * 4 + (i - 4)));
    float bsv = bias[row];
    float4 o0, o1;
    o0.x = acc[i][0] + bsv; o0.y = acc[i][1] + bsv;
    o0.z = acc[i][2] + bsv; o0.w = acc[i][3] + bsv;
    o1.x = acc[i][4] + bsv; o1.y = acc[i][5] + bsv;
    o1.z = acc[i][6] + bsv; o1.w = acc[i][7] + bsv;
    if (RELU) {
      o0.x = fmaxf(o0.x, 0.f); o0.y = fmaxf(o0.y, 0.f);
      o0.z = fmaxf(o0.z, 0.f); o0.w = fmaxf(o0.w, 0.f);
      o1.x = fmaxf(o1.x, 0.f); o1.y = fmaxf(o1.y, 0.f);
      o1.z = fmaxf(o1.z, 0.f); o1.w = fmaxf(o1.w, 0.f);
    }
    float* crow = Cp + (size_t)row * Tt + bn;
    *(float4*)(crow + tx * 4) = o0;
    *(float4*)(crow + 64 + tx * 4) = o1;
  }
}

// ---------------- fused Wout GEMM + GLU ----------------
// A = Wout (768 x 384). Block computes rows [bm,bm+64) of both halves (a: rows bm..,
// g: rows 384+bm..) x 128 cols, epilogue writes (a+ba)*sigmoid(g+bg) -> (B,384,T).
__global__ __launch_bounds__(256) void gemm_glu_kernel(
    const float* __restrict__ A, const float* __restrict__ Bg,
    const float* __restrict__ bias, float* __restrict__ Cg) {
  __shared__ float Aa[8][64];
  __shared__ float Ag[8][64];
  __shared__ float Bs[8][128];
  int tid = threadIdx.x;
  int bz = blockIdx.z;
  const float* Bp = Bg + (size_t)bz * Hc * Tt;
  float* Cp = Cg + (size_t)bz * Hc * Tt;
  int bm = blockIdx.y * 64, bn = blockIdx.x * 128;
  int half = tid >> 7;        // wave-uniform: waves 0,1 stage a-rows; waves 2,3 stage g-rows
  int am = (tid & 127) >> 1;  // 0..63
  int ak = (tid & 1) * 4;
  int bk = tid >> 5, bn4 = (tid & 31) * 4;
  int tx = tid & 15, ty = tid >> 4;
  float acc_a[4][8], acc_g[4][8];
#pragma unroll
  for (int i = 0; i < 4; i++)
#pragma unroll
    for (int j = 0; j < 8; j++) { acc_a[i][j] = 0.f; acc_g[i][j] = 0.f; }
  const float* Aptr = A + (size_t)(half * 384 + bm + am) * Hc + ak;
  const float* Bptr = Bp + (size_t)bk * Tt + bn + bn4;
  float* Ah = half ? &Ag[0][0] : &Aa[0][0];
  for (int k0 = 0; k0 < Hc; k0 += 8) {
    float4 av = *(const float4*)(Aptr + k0);
    float4 bv = *(const float4*)(Bptr + (size_t)k0 * Tt);
    __syncthreads();
    Ah[(ak + 0) * 64 + am] = av.x; Ah[(ak + 1) * 64 + am] = av.y;
    Ah[(ak + 2) * 64 + am] = av.z; Ah[(ak + 3) * 64 + am] = av.w;
    *(float4*)&Bs[bk][bn4] = bv;
    __syncthreads();
#pragma unroll
    for (int kk = 0; kk < 8; kk++) {
      float a4[4], g4[4], bb[8];
      *(float4*)&a4[0] = *(const float4*)&Aa[kk][ty * 4];
      *(float4*)&g4[0] = *(const float4*)&Ag[kk][ty * 4];
      *(float4*)&bb[0] = *(const float4*)&Bs[kk][tx * 4];
      *(float4*)&bb[4] = *(const float4*)&Bs[kk][64 + tx * 4];
#pragma unroll
      for (int i = 0; i < 4; i++)
#pragma unroll
        for (int j = 0; j < 8; j++) {
          acc_a[i][j] = fmaf(a4[i], bb[j], acc_a[i][j]);
          acc_g[i][j] = fmaf(g4[i], bb[j], acc_g[i][j]);
        }
    }
  }
#pragma unroll
  for (int i = 0; i < 4; i++) {
    int row = bm + ty * 4 + i;
    float ba = bias[row], bg = bias[384 + row];
    float4 o0, o1;
    float av0, gv0;
    av0 = acc_a[i][0] + ba; gv0 = acc_g[i][0] + bg; o0.x = av0 / (1.f + expf(-gv0));
    av0 = acc_a[i][1] + ba; gv0 = acc_g[i][1] + bg; o0.y = av0 / (1.f + expf(-gv0));
    av0 = acc_a[i][2] + ba; gv0 = acc_g[i][2] + bg; o0.z = av0 / (1.f + expf(-gv0));
    av0 = acc_a[i][3] + ba; gv0 = acc_g[i][3] + bg; o0.w = av0 / (1.f + expf(-gv0));
    av0 = acc_a[i][4] + ba; gv0 = acc_g[i][4] + bg; o1.x = av0 / (1.f + expf(-gv0));
    av0 = acc_a[i][5] + ba; gv0 = acc_g[i][5] + bg; o1.y = av0 / (1.f + expf(-gv0));
    av0 = acc_a[i][6] + ba; gv0 = acc_g[i][6] + bg; o1.z = av0 / (1.f + expf(-gv0));
    av0 = acc_a[i][7] + ba; gv0 = acc_g[i][7] + bg; o1.w = av0 / (1.f + expf(-gv0));
    float* crow = Cp + (size_t)row * Tt + bn;
    *(float4*)(crow + tx * 4) = o0;
    *(float4*)(crow + 64 + tx * 4) = o1;
  }
}

// ---------------- LayerNorm over channel dim (axis 1), input = in1*f1 + in2*f2 ----------------
__global__ __launch_bounds__(256) void ln_kernel(
    const float* __restrict__ in1, const float* __restrict__ in2,
    const float* __restrict__ mask, const float* __restrict__ gamma,
    const float* __restrict__ beta, float* __restrict__ out,
    int m1, int m2) {
  int col = blockIdx.x * 256 + threadIdx.x;  // B*T
  int b = col >> 11;                         // T = 2048
  int t = col & (Tt - 1);
  float mv = mask[(size_t)b * Tt + t];
  float f1 = m1 ? mv : 1.f;
  float f2 = m2 ? mv : 1.f;
  const float* p1 = in1 + (size_t)b * Hc * Tt + t;
  const float* p2 = in2 + (size_t)b * Hc * Tt + t;
  float sum = 0.f, sq = 0.f;
  for (int hh = 0; hh < Hc; hh++) {
    float v = p1[(size_t)hh * Tt] * f1 + p2[(size_t)hh * Tt] * f2;
    sum += v; sq = fmaf(v, v, sq);
  }
  float m = sum * (1.f / Hc);
  float var = sq * (1.f / Hc) - m * m;
  float rs = rsqrtf(var + 1e-4f);
  float* po = out + (size_t)b * Hc * Tt + t;
  for (int hh = 0; hh < Hc; hh++) {
    float v = p1[(size_t)hh * Tt] * f1 + p2[(size_t)hh * Tt] * f2;
    po[(size_t)hh * Tt] = (v - m) * rs * gamma[hh] + beta[hh];
  }
}

// ---------------- final mask multiply (in place on d_out) ----------------
__global__ void maskmul_kernel(const float* __restrict__ x, const float* __restrict__ mask,
                               float* __restrict__ out) {
  int idx = blockIdx.x * 256 + threadIdx.x;  // NX/4
  size_t e = (size_t)idx * 4;
  int b = (int)(e / ((size_t)Hc * Tt));
  int t = (int)(e & (Tt - 1));
  float4 xv = *(const float4*)(x + e);
  float4 mv = *(const float4*)(mask + (size_t)b * Tt + t);
  float4 o;
  o.x = xv.x * mv.x; o.y = xv.y * mv.y; o.z = xv.z * mv.z; o.w = xv.w * mv.w;
  *(float4*)(out + e) = o;
}

// ---------------- diagnostic: signal insufficient workspace ----------------
__global__ void diag_kernel(float* out, float v) {
  if (blockIdx.x == 0 && threadIdx.x == 0) out[0] = v;
}

extern "C" void kernel_launch(void* const* d_in, const int* in_sizes, int n_in,
                              void* d_out, int out_size, void* d_ws, size_t ws_size,
                              hipStream_t stream) {
  const float* x_in  = (const float*)d_in[0];
  const float* xmask = (const float*)d_in[1];
  const float* log_dt = (const float*)d_in[2];
  const float* A_re = (const float*)d_in[3];
  const float* A_im = (const float*)d_in[4];
  const float* C_re = (const float*)d_in[5];
  const float* C_im = (const float*)d_in[6];
  const float* Dv   = (const float*)d_in[7];
  const float* Wout = (const float*)d_in[8];
  const float* bout = (const float*)d_in[9];
  const float* g1   = (const float*)d_in[10];
  const float* be1  = (const float*)d_in[11];
  const float* W1   = (const float*)d_in[12];
  const float* bf1  = (const float*)d_in[13];
  const float* W2   = (const float*)d_in[14];
  const float* bf2  = (const float*)d_in[15];
  const float* g2   = (const float*)d_in[16];
  const float* be2  = (const float*)d_in[17];

  const size_t NX  = (size_t)Bq * Hc * Tt;            // 12,582,912 floats (50 MB)
  const size_t NP  = (size_t)LYR * Hc * N2;           // 73,728
  const size_t HB1 = (size_t)HFq * Tt;                // hidden floats per batch (3.1M)

  // ws layout: ybuf(NX) | glubuf(NX, overlaid w/ scan states) | params(6*NP) | hbuf(nb*HB1)
  const size_t baseF = 2 * NX + 6 * NP;
  size_t wsF = ws_size / 4;
  if (wsF < baseF + HB1) {
    // signal actual workspace size via absmax: 1000 + MB
    diag_kernel<<<1, 64, 0, stream>>>((float*)d_out, 1000.0f + (float)(ws_size >> 20));
    return;
  }
  int nb = (int)((wsF - baseF) / HB1);
  if (nb > Bq) nb = Bq;

  float* ws = (float*)d_ws;
  float* ybuf   = ws;                 // NX : scan y; later x1 (post-LN1)
  float* glubuf = ws + NX;            // NX : scan states overlay -> glu out -> ffn2 out
  float* stbuf  = glubuf;             // overlay (NST=6.3M < NX, dead before glu written)
  float* wre  = ws + 2 * NX;
  float* wim  = wre + NP;
  float* cdre = wim + NP;
  float* cdim = cdre + NP;
  float* wSre = cdim + NP;
  float* wSim = wSre + NP;
  float* hbuf = wSim + NP;            // nb * HB1
  float* xbuf = (float*)d_out;        // layer ping buffer lives in d_out (50 MB free)

  param_kernel<<<(LYR * Hc * N2 + 255) / 256, 256, 0, stream>>>(
      log_dt, A_re, A_im, C_re, C_im, wre, wim, cdre, cdim, wSre, wSim);

  for (int i = 0; i < LYR; i++) {
    const float* xin = (i == 0) ? x_in : xbuf;
    size_t po = (size_t)i * Hc * N2;

    // --- S4D scan: y = gelu(ssm(x*mask) + D*(x*mask)) -> ybuf
    scan_local<<<(Bq * Hc * NCH) / 256, 256, 0, stream>>>(xin, xmask, wre + po, wim + po, stbuf);
    scan_prefix<<<(Bq * Hc + 255) / 256, 256, 0, stream>>>(stbuf, wSre + po, wSim + po);
    scan_out<<<(Bq * Hc * NCH) / 256, 256, 0, stream>>>(
        xin, xmask, wre + po, wim + po, cdre + po, cdim + po, Dv + (size_t)i * Hc, stbuf, ybuf);

    // --- glu = GLU(Wout*y + bout) -> glubuf (fused, no z materialization)
    gemm_glu_kernel<<<dim3(Tt / 128, Hc / 64, Bq), 256, 0, stream>>>(
        Wout + (size_t)i * TWOH * Hc, ybuf, bout + (size_t)i * TWOH, glubuf);

    // --- x1 = LN(x*mask + glu) -> ybuf (y is dead)
    ln_kernel<<<(Bq * Tt) / 256, 256, 0, stream>>>(
        xin, glubuf, xmask, g1 + (size_t)i * Hc, be1 + (size_t)i * Hc, ybuf, 1, 0);

    // --- FFN, batch-chunked through hbuf (nb batches at a time)
    for (int b0 = 0; b0 < Bq; b0 += nb) {
      int nbc = (Bq - b0 < nb) ? (Bq - b0) : nb;
      // h = relu(W1*(x1*mask) + bf1)
      gemm_kernel<1, 1><<<dim3(Tt / 128, HFq / 128, nbc), 256, 0, stream>>>(
          W1 + (size_t)i * HFq * Hc, ybuf + (size_t)b0 * Hc * Tt, bf1 + (size_t)i * HFq,
          xmask + (size_t)b0 * Tt, hbuf, HFq, Hc);
      // f = W2*(h*mask) + bf2 -> glubuf (glu dead)
      gemm_kernel<0, 1><<<dim3(Tt / 128, Hc / 128, nbc), 256, 0, stream>>>(
          W2 + (size_t)i * Hc * HFq, hbuf, bf2 + (size_t)i * Hc,
          xmask + (size_t)b0 * Tt, glubuf + (size_t)b0 * Hc * Tt, Hc, HFq);
    }

    // --- x = LN(x1 + f*mask) -> xbuf (d_out)
    ln_kernel<<<(Bq * Tt) / 256, 256, 0, stream>>>(
        ybuf, glubuf, xmask, g2 + (size_t)i * Hc, be2 + (size_t)i * Hc, xbuf, 0, 1);
  }

  maskmul_kernel<<<(int)((NX / 4) / 256), 256, 0, stream>>>(xbuf, xmask, (float*)d_out);
}

// Round 3
// 3378.201 us; speedup vs baseline: 3.0575x; 3.0575x over previous
//
#include <hip/hip_runtime.h>
#include <math.h>

#define Bq 16
#define Hc 384
#define Tt 2048
#define N2 32
#define LYR 6
#define HFq 1536
#define TWOH 768
#define CHUNK 128
#define NCH (Tt/CHUNK)   // 16

typedef __bf16 bf16x8 __attribute__((ext_vector_type(8)));
typedef float floatx4 __attribute__((ext_vector_type(4)));

__device__ __forceinline__ unsigned short bfbits(float f) {
  union { float f; unsigned u; } x; x.f = f;
  return (unsigned short)((x.u + 0x7FFF + ((x.u >> 16) & 1)) >> 16);
}

// ---------------- param precompute (fp64 for accuracy) ----------------
__global__ void param_kernel(const float* __restrict__ log_dt,
                             const float* __restrict__ A_re, const float* __restrict__ A_im,
                             const float* __restrict__ C_re, const float* __restrict__ C_im,
                             float* __restrict__ wre, float* __restrict__ wim,
                             float* __restrict__ cdre, float* __restrict__ cdim,
                             float* __restrict__ wSre, float* __restrict__ wSim) {
  int idx = blockIdx.x * blockDim.x + threadIdx.x;
  if (idx >= LYR * Hc * N2) return;
  int hn = idx / N2;
  double dt = exp((double)log_dt[hn]);
  double are = (double)A_re[idx], aim = (double)A_im[idx];
  double dre = are * dt, dimv = aim * dt;
  double er = exp(dre);
  double wr = er * cos(dimv), wi_ = er * sin(dimv);
  double den = are * are + aim * aim;
  double nr = wr - 1.0, ni = wi_;
  double qr = (nr * are + ni * aim) / den;
  double qi = (ni * are - nr * aim) / den;
  double cr = (double)C_re[idx], ci = (double)C_im[idx];
  cdre[idx] = (float)(2.0 * (cr * qr - ci * qi));
  cdim[idx] = (float)(2.0 * (cr * qi + ci * qr));
  wre[idx] = (float)wr; wim[idx] = (float)wi_;
  double es = exp(dre * (double)CHUNK);
  wSre[idx] = (float)(es * cos(dimv * (double)CHUNK));
  wSim[idx] = (float)(es * sin(dimv * (double)CHUNK));
}

// ---------------- weight fp32 -> bf16 (RNE) ----------------
__global__ void cvt_bf16_kernel(const float* __restrict__ in, unsigned short* __restrict__ out,
                                int n4) {
  int idx = blockIdx.x * 256 + threadIdx.x;
  if (idx >= n4) return;
  float4 v = ((const float4*)in)[idx];
  ushort4 o;
  o.x = bfbits(v.x); o.y = bfbits(v.y); o.z = bfbits(v.z); o.w = bfbits(v.w);
  ((ushort4*)out)[idx] = o;
}

// ---------------- transpose (B,C,T) -> (B,T,C) ----------------
__global__ __launch_bounds__(256) void transpose_fwd(const float* __restrict__ in,
                                                     float* __restrict__ out) {
  __shared__ float tile[32][33];
  int tx = threadIdx.x, ty = threadIdx.y;
  int t0 = blockIdx.x * 32, c0 = blockIdx.y * 32, b = blockIdx.z;
#pragma unroll
  for (int k = 0; k < 4; k++)
    tile[ty + 8 * k][tx] = in[((size_t)(b * Hc + c0 + ty + 8 * k)) * Tt + t0 + tx];
  __syncthreads();
#pragma unroll
  for (int k = 0; k < 4; k++)
    out[((size_t)(b * Tt + t0 + ty + 8 * k)) * Hc + c0 + tx] = tile[tx][ty + 8 * k];
}

// ---------------- transpose (B,T,C) -> (B,C,T) with mask ----------------
__global__ __launch_bounds__(256) void transpose_bwd(const float* __restrict__ in,
                                                     const float* __restrict__ mask,
                                                     float* __restrict__ out) {
  __shared__ float tile[32][33];
  int tx = threadIdx.x, ty = threadIdx.y;
  int t0 = blockIdx.x * 32, c0 = blockIdx.y * 32, b = blockIdx.z;
#pragma unroll
  for (int k = 0; k < 4; k++)
    tile[ty + 8 * k][tx] = in[((size_t)(b * Tt + t0 + ty + 8 * k)) * Hc + c0 + tx];
  __syncthreads();
  float mv = mask[(size_t)b * Tt + t0 + tx];
#pragma unroll
  for (int k = 0; k < 4; k++)
    out[((size_t)(b * Hc + c0 + ty + 8 * k)) * Tt + t0 + tx] = tile[tx][ty + 8 * k] * mv;
}

// ---------------- scan phase 1: chunk-local states, (B,T,C) input ----------------
__global__ __launch_bounds__(128) void scan_local_t(
    const float* __restrict__ xT, const float* __restrict__ mask,
    const float* __restrict__ wre, const float* __restrict__ wim,
    float* __restrict__ states) {
  int h = blockIdx.y * 128 + threadIdx.x;
  int c = blockIdx.x, b = blockIdx.z;
  float wr[N2], wi[N2], sr[N2], si[N2];
#pragma unroll
  for (int n = 0; n < N2; n++) {
    wr[n] = wre[h * N2 + n]; wi[n] = wim[h * N2 + n];
    sr[n] = 0.f; si[n] = 0.f;
  }
  const float* xp = xT + ((size_t)(b * Tt + c * CHUNK)) * Hc + h;
  const float* mp = mask + (size_t)b * Tt + c * CHUNK;
  for (int t = 0; t < CHUNK; t++) {
    float u = xp[(size_t)t * Hc] * mp[t];
#pragma unroll
    for (int n = 0; n < N2; n++) {
      float s0 = sr[n];
      sr[n] = fmaf(wr[n], s0, fmaf(-wi[n], si[n], u));
      si[n] = fmaf(wr[n], si[n], wi[n] * s0);
    }
  }
  float* sp = states + (((size_t)(b * Hc + h)) * NCH + c) * (2 * N2);
#pragma unroll
  for (int n = 0; n < N2; n++) { sp[2 * n] = sr[n]; sp[2 * n + 1] = si[n]; }
}

// ---------------- scan phase 2: prefix over chunks (unchanged layout) ----------------
__global__ __launch_bounds__(256, 1) void scan_prefix(
    float* __restrict__ states,
    const float* __restrict__ wSre, const float* __restrict__ wSim) {
  int tid = blockIdx.x * 256 + threadIdx.x;  // B*H
  if (tid >= Bq * Hc) return;
  int h = tid % Hc;
  float wr[N2], wi[N2], cr_[N2], ci_[N2];
#pragma unroll
  for (int n = 0; n < N2; n++) {
    wr[n] = wSre[h * N2 + n]; wi[n] = wSim[h * N2 + n];
    cr_[n] = 0.f; ci_[n] = 0.f;
  }
  float* base = states + (size_t)tid * NCH * 2 * N2;
  for (int c = 0; c < NCH; c++) {
    float* sp = base + c * 2 * N2;
#pragma unroll
    for (int n = 0; n < N2; n++) {
      float lr = sp[2 * n], li = sp[2 * n + 1];
      sp[2 * n] = cr_[n]; sp[2 * n + 1] = ci_[n];
      float c0 = cr_[n];
      cr_[n] = fmaf(wr[n], c0, fmaf(-wi[n], ci_[n], lr));
      ci_[n] = fmaf(wr[n], ci_[n], fmaf(wi[n], c0, li));
    }
  }
}

// ---------------- scan phase 3: y = gelu(ssm + D*x), write bf16 (B,T,C) ----------------
__global__ __launch_bounds__(128) void scan_out_t(
    const float* __restrict__ xT, const float* __restrict__ mask,
    const float* __restrict__ wre, const float* __restrict__ wim,
    const float* __restrict__ cdre, const float* __restrict__ cdim,
    const float* __restrict__ Dv, const float* __restrict__ states,
    unsigned short* __restrict__ ybf) {
  int h = blockIdx.y * 128 + threadIdx.x;
  int c = blockIdx.x, b = blockIdx.z;
  float wr[N2], wi[N2], cdr[N2], cdi[N2], sr[N2], si[N2];
  const float* sp = states + (((size_t)(b * Hc + h)) * NCH + c) * (2 * N2);
#pragma unroll
  for (int n = 0; n < N2; n++) {
    wr[n] = wre[h * N2 + n]; wi[n] = wim[h * N2 + n];
    cdr[n] = cdre[h * N2 + n]; cdi[n] = cdim[h * N2 + n];
    sr[n] = sp[2 * n]; si[n] = sp[2 * n + 1];
  }
  float d = Dv[h];
  const float* xp = xT + ((size_t)(b * Tt + c * CHUNK)) * Hc + h;
  const float* mp = mask + (size_t)b * Tt + c * CHUNK;
  unsigned short* yp = ybf + ((size_t)(b * Tt + c * CHUNK)) * Hc + h;
  for (int t = 0; t < CHUNK; t++) {
    float u = xp[(size_t)t * Hc] * mp[t];
    float acc = 0.f;
#pragma unroll
    for (int n = 0; n < N2; n++) {
      float s0 = sr[n];
      sr[n] = fmaf(wr[n], s0, fmaf(-wi[n], si[n], u));
      si[n] = fmaf(wr[n], si[n], wi[n] * s0);
      acc = fmaf(cdr[n], sr[n], fmaf(-cdi[n], si[n], acc));
    }
    float v = fmaf(d, u, acc);
    v = 0.5f * v * (1.0f + erff(v * 0.70710678118654752f));
    yp[(size_t)t * Hc] = bfbits(v);
  }
}

// ---------------- MFMA GEMM: out(B,T,N) = act(B,T,K) x W(N,K)^T ----------------
// EPI 0: outf = acc + bias                (fp32)
// EPI 1: outb = relu(acc + bias) * mask   (bf16)
// EPI 2: GLU: W has 2N rows; outf = (a+ba)*sigmoid(g+bg)  (fp32)
template <int EPI>
__global__ __launch_bounds__(256) void mfma_gemm(
    const __bf16* __restrict__ act, const __bf16* __restrict__ W,
    const float* __restrict__ bias, const float* __restrict__ mask,
    float* __restrict__ outf, unsigned short* __restrict__ outb,
    int K, int NOUT) {
  __shared__ __bf16 As[128][32];
  __shared__ __bf16 Bs[128][32];
  __shared__ __bf16 Bs2[(EPI == 2) ? 128 : 1][32];
  int tid = threadIdx.x;
  int b = blockIdx.z;
  int t0 = blockIdx.x * 128, n0 = blockIdx.y * 128;
  int wave = tid >> 6, lane = tid & 63, l16 = lane & 15, quad = lane >> 4;
  int wm = wave >> 1, wn = wave & 1;
  int sr = tid >> 2, sk = (tid & 3) * 8;

  floatx4 acc[4][4];
  floatx4 accg[(EPI == 2) ? 4 : 1][4];
#pragma unroll
  for (int i = 0; i < 4; i++)
#pragma unroll
    for (int j = 0; j < 4; j++) {
      acc[i][j] = (floatx4){0.f, 0.f, 0.f, 0.f};
      if constexpr (EPI == 2) accg[i][j] = (floatx4){0.f, 0.f, 0.f, 0.f};
    }

  const __bf16* aPtr = act + ((size_t)(b * Tt + t0 + sr)) * K + sk;
  const __bf16* bPtr = W + (size_t)(n0 + sr) * K + sk;
  const __bf16* gPtr = (EPI == 2) ? (W + (size_t)(NOUT + n0 + sr) * K + sk) : bPtr;

  for (int k0 = 0; k0 < K; k0 += 32) {
    uint4 a0 = *(const uint4*)(aPtr + k0);
    uint4 a1 = *(const uint4*)(aPtr + k0 + (size_t)64 * K);
    uint4 w0 = *(const uint4*)(bPtr + k0);
    uint4 w1 = *(const uint4*)(bPtr + k0 + (size_t)64 * K);
    uint4 g0, g1;
    if constexpr (EPI == 2) {
      g0 = *(const uint4*)(gPtr + k0);
      g1 = *(const uint4*)(gPtr + k0 + (size_t)64 * K);
    }
    __syncthreads();
    *(uint4*)&As[sr][sk] = a0; *(uint4*)&As[sr + 64][sk] = a1;
    *(uint4*)&Bs[sr][sk] = w0; *(uint4*)&Bs[sr + 64][sk] = w1;
    if constexpr (EPI == 2) { *(uint4*)&Bs2[sr][sk] = g0; *(uint4*)&Bs2[sr + 64][sk] = g1; }
    __syncthreads();
    bf16x8 af[4], bfr[4], gfr[(EPI == 2) ? 4 : 1];
#pragma unroll
    for (int i = 0; i < 4; i++)
      af[i] = *(const bf16x8*)&As[wm * 64 + i * 16 + l16][quad * 8];
#pragma unroll
    for (int j = 0; j < 4; j++) {
      bfr[j] = *(const bf16x8*)&Bs[wn * 64 + j * 16 + l16][quad * 8];
      if constexpr (EPI == 2)
        gfr[j] = *(const bf16x8*)&Bs2[wn * 64 + j * 16 + l16][quad * 8];
    }
#pragma unroll
    for (int i = 0; i < 4; i++)
#pragma unroll
      for (int j = 0; j < 4; j++) {
        acc[i][j] = __builtin_amdgcn_mfma_f32_16x16x32_bf16(af[i], bfr[j], acc[i][j], 0, 0, 0);
        if constexpr (EPI == 2)
          accg[i][j] = __builtin_amdgcn_mfma_f32_16x16x32_bf16(af[i], gfr[j], accg[i][j], 0, 0, 0);
      }
  }

  // epilogue: D row = t (i*16 + quad*4 + r), col = n (j*16 + l16)
#pragma unroll
  for (int i = 0; i < 4; i++) {
    int tb = t0 + wm * 64 + i * 16 + quad * 4;
    float mv[4];
    if constexpr (EPI == 1) {
#pragma unroll
      for (int r = 0; r < 4; r++) mv[r] = mask[(size_t)b * Tt + tb + r];
    }
#pragma unroll
    for (int j = 0; j < 4; j++) {
      int n = n0 + wn * 64 + j * 16 + l16;
      float bn = bias[n];
      float bg = (EPI == 2) ? bias[NOUT + n] : 0.f;
#pragma unroll
      for (int r = 0; r < 4; r++) {
        size_t o = ((size_t)(b * Tt + tb + r)) * NOUT + n;
        if constexpr (EPI == 0) {
          outf[o] = acc[i][j][r] + bn;
        } else if constexpr (EPI == 1) {
          float v = fmaxf(acc[i][j][r] + bn, 0.f) * mv[r];
          outb[o] = bfbits(v);
        } else {
          float a = acc[i][j][r] + bn;
          float g = accg[i][j][r] + bg;
          outf[o] = a / (1.f + expf(-g));
        }
      }
    }
  }
}

// ---------------- LayerNorm over C (contiguous), wave per row ----------------
// in = in1*f1 + in2*f2 ; out fp32; optional outb = bf16(out * mask)
__global__ __launch_bounds__(256) void ln_t(
    const float* __restrict__ in1, const float* __restrict__ in2,
    const float* __restrict__ mask, const float* __restrict__ gamma,
    const float* __restrict__ beta, float* __restrict__ out,
    unsigned short* __restrict__ outb, int m1, int m2) {
  int row = blockIdx.x * 4 + (threadIdx.x >> 6);  // b*Tt + t
  int lane = threadIdx.x & 63;
  float mv = mask[row];
  float f1 = m1 ? mv : 1.f;
  float f2 = m2 ? mv : 1.f;
  size_t base = (size_t)row * Hc;
  float v[6], sum = 0.f, sq = 0.f;
#pragma unroll
  for (int j = 0; j < 6; j++) {
    int idx = lane + 64 * j;
    float a = in1[base + idx] * f1 + in2[base + idx] * f2;
    v[j] = a; sum += a; sq = fmaf(a, a, sq);
  }
#pragma unroll
  for (int off = 32; off >= 1; off >>= 1) {
    sum += __shfl_xor(sum, off, 64);
    sq  += __shfl_xor(sq,  off, 64);
  }
  float m = sum * (1.f / Hc);
  float var = sq * (1.f / Hc) - m * m;
  float rs = rsqrtf(var + 1e-4f);
#pragma unroll
  for (int j = 0; j < 6; j++) {
    int idx = lane + 64 * j;
    float o = (v[j] - m) * rs * gamma[idx] + beta[idx];
    out[base + idx] = o;
    if (outb) outb[base + idx] = bfbits(o * mv);
  }
}

// ---------------- diagnostic ----------------
__global__ void diag_kernel(float* out, float v) {
  if (blockIdx.x == 0 && threadIdx.x == 0) out[0] = v;
}

extern "C" void kernel_launch(void* const* d_in, const int* in_sizes, int n_in,
                              void* d_out, int out_size, void* d_ws, size_t ws_size,
                              hipStream_t stream) {
  const float* x_in  = (const float*)d_in[0];
  const float* xmask = (const float*)d_in[1];
  const float* log_dt = (const float*)d_in[2];
  const float* A_re = (const float*)d_in[3];
  const float* A_im = (const float*)d_in[4];
  const float* C_re = (const float*)d_in[5];
  const float* C_im = (const float*)d_in[6];
  const float* Dv   = (const float*)d_in[7];
  const float* Wout = (const float*)d_in[8];
  const float* bout = (const float*)d_in[9];
  const float* g1   = (const float*)d_in[10];
  const float* be1  = (const float*)d_in[11];
  const float* W1   = (const float*)d_in[12];
  const float* bf1  = (const float*)d_in[13];
  const float* W2   = (const float*)d_in[14];
  const float* bf2  = (const float*)d_in[15];
  const float* g2   = (const float*)d_in[16];
  const float* be2  = (const float*)d_in[17];

  const size_t NXf   = (size_t)Bq * Hc * Tt;          // 12,582,912 floats
  const size_t NP    = (size_t)LYR * Hc * N2;         // 73,728
  const size_t YBFf  = NXf / 2;                       // bf16 y / x1b region, in floats
  const size_t HBFf  = (size_t)Bq * Tt * HFq / 2;     // bf16 h region, in floats
  const size_t WOUTf = (size_t)LYR * TWOH * Hc / 2;
  const size_t W1f   = (size_t)LYR * HFq * Hc / 2;
  const size_t W2f   = (size_t)LYR * Hc * HFq / 2;

  size_t need = 2 * NXf + YBFf + HBFf + WOUTf + W1f + W2f + 6 * NP;
  if (ws_size / 4 < need) {
    diag_kernel<<<1, 64, 0, stream>>>((float*)d_out, 1000.0f + (float)(ws_size >> 20));
    return;
  }

  float* ws = (float*)d_ws;
  float* xT   = ws;                       // (B,T,C) fp32 layer state
  float* tmp  = xT + NXf;                 // (B,T,C) fp32: glu out, then ffn2 out
  float* ybfF = tmp + NXf;                // bf16 (B,T,C): y, then x1*mask
  float* hbfF = ybfF + YBFf;              // bf16 (B,T,HF): ffn hidden; scan-states overlay
  float* wobF = hbfF + HBFf;              // bf16 weights
  float* w1bF = wobF + WOUTf;
  float* w2bF = w1bF + W1f;
  float* wre  = w2bF + W2f;
  float* wim  = wre + NP;
  float* cdre = wim + NP;
  float* cdim = cdre + NP;
  float* wSre = cdim + NP;
  float* wSim = wSre + NP;

  unsigned short* ybf = (unsigned short*)ybfF;
  unsigned short* hbf = (unsigned short*)hbfF;
  float* stbuf = hbfF;                    // states overlay (6.3M < 25.2M floats)
  unsigned short* wob = (unsigned short*)wobF;
  unsigned short* w1b = (unsigned short*)w1bF;
  unsigned short* w2b = (unsigned short*)w2bF;
  float* x1 = (float*)d_out;              // (B,T,C) fp32 post-LN1 lives in d_out

  param_kernel<<<(LYR * Hc * N2 + 255) / 256, 256, 0, stream>>>(
      log_dt, A_re, A_im, C_re, C_im, wre, wim, cdre, cdim, wSre, wSim);
  cvt_bf16_kernel<<<(int)(2 * WOUTf + 1023) / 1024, 256, 0, stream>>>(Wout, wob, (int)(WOUTf / 2));
  cvt_bf16_kernel<<<(int)(2 * W1f + 1023) / 1024, 256, 0, stream>>>(W1, w1b, (int)(W1f / 2));
  cvt_bf16_kernel<<<(int)(2 * W2f + 1023) / 1024, 256, 0, stream>>>(W2, w2b, (int)(W2f / 2));
  transpose_fwd<<<dim3(Tt / 32, Hc / 32, Bq), dim3(32, 8), 0, stream>>>(x_in, xT);

  for (int i = 0; i < LYR; i++) {
    size_t po = (size_t)i * Hc * N2;

    scan_local_t<<<dim3(NCH, Hc / 128, Bq), 128, 0, stream>>>(xT, xmask, wre + po, wim + po, stbuf);
    scan_prefix<<<(Bq * Hc + 255) / 256, 256, 0, stream>>>(stbuf, wSre + po, wSim + po);
    scan_out_t<<<dim3(NCH, Hc / 128, Bq), 128, 0, stream>>>(
        xT, xmask, wre + po, wim + po, cdre + po, cdim + po, Dv + (size_t)i * Hc, stbuf, ybf);

    // glu = GLU(Wout*y + bout) -> tmp (fp32)
    mfma_gemm<2><<<dim3(Tt / 128, Hc / 128, Bq), 256, 0, stream>>>(
        (const __bf16*)ybf, (const __bf16*)(wob + (size_t)i * TWOH * Hc),
        bout + (size_t)i * TWOH, xmask, tmp, nullptr, Hc, Hc);

    // x1 = LN(x*mask + glu) -> d_out fp32 ; x1b = bf16(x1*mask) -> ybf
    ln_t<<<(Bq * Tt) / 4, 256, 0, stream>>>(
        xT, tmp, xmask, g1 + (size_t)i * Hc, be1 + (size_t)i * Hc, x1, ybf, 1, 0);

    // h = bf16(relu(W1*x1b + bf1) * mask) -> hbf
    mfma_gemm<1><<<dim3(Tt / 128, HFq / 128, Bq), 256, 0, stream>>>(
        (const __bf16*)ybf, (const __bf16*)(w1b + (size_t)i * HFq * Hc),
        bf1 + (size_t)i * HFq, xmask, nullptr, hbf, Hc, HFq);

    // f = W2*h + bf2 -> tmp (fp32)
    mfma_gemm<0><<<dim3(Tt / 128, Hc / 128, Bq), 256, 0, stream>>>(
        (const __bf16*)hbf, (const __bf16*)(w2b + (size_t)i * Hc * HFq),
        bf2 + (size_t)i * Hc, xmask, tmp, nullptr, HFq, Hc);

    // x = LN(x1 + f*mask) -> xT
    ln_t<<<(Bq * Tt) / 4, 256, 0, stream>>>(
        x1, tmp, xmask, g2 + (size_t)i * Hc, be2 + (size_t)i * Hc, xT, nullptr, 0, 1);
  }

  transpose_bwd<<<dim3(Tt / 32, Hc / 32, Bq), dim3(32, 8), 0, stream>>>(xT, xmask, (float*)d_out);
}

// Round 4
// 2454.120 us; speedup vs baseline: 4.2088x; 1.3765x over previous
//
#include <hip/hip_runtime.h>
#include <math.h>

#define Bq 16
#define Hc 384
#define Tt 2048
#define N2 32
#define LYR 6
#define HFq 1536
#define TWOH 768
#define CHUNK 128
#define NCH (Tt/CHUNK)   // 16

typedef __bf16 bf16x8 __attribute__((ext_vector_type(8)));
typedef float floatx4 __attribute__((ext_vector_type(4)));

__device__ __forceinline__ unsigned short bfbits(float f) {
  union { float f; unsigned u; } x; x.f = f;
  return (unsigned short)((x.u + 0x7FFF + ((x.u >> 16) & 1)) >> 16);
}

// ---------------- param precompute (fp64 for accuracy) ----------------
__global__ void param_kernel(const float* __restrict__ log_dt,
                             const float* __restrict__ A_re, const float* __restrict__ A_im,
                             const float* __restrict__ C_re, const float* __restrict__ C_im,
                             float* __restrict__ wre, float* __restrict__ wim,
                             float* __restrict__ cdre, float* __restrict__ cdim,
                             float* __restrict__ wSre, float* __restrict__ wSim) {
  int idx = blockIdx.x * blockDim.x + threadIdx.x;
  if (idx >= LYR * Hc * N2) return;
  int hn = idx / N2;
  double dt = exp((double)log_dt[hn]);
  double are = (double)A_re[idx], aim = (double)A_im[idx];
  double dre = are * dt, dimv = aim * dt;
  double er = exp(dre);
  double wr = er * cos(dimv), wi_ = er * sin(dimv);
  double den = are * are + aim * aim;
  double nr = wr - 1.0, ni = wi_;
  double qr = (nr * are + ni * aim) / den;
  double qi = (ni * are - nr * aim) / den;
  double cr = (double)C_re[idx], ci = (double)C_im[idx];
  cdre[idx] = (float)(2.0 * (cr * qr - ci * qi));
  cdim[idx] = (float)(2.0 * (cr * qi + ci * qr));
  wre[idx] = (float)wr; wim[idx] = (float)wi_;
  double es = exp(dre * (double)CHUNK);
  wSre[idx] = (float)(es * cos(dimv * (double)CHUNK));
  wSim[idx] = (float)(es * sin(dimv * (double)CHUNK));
}

// ---------------- weight fp32 -> bf16 (RNE) ----------------
__global__ void cvt_bf16_kernel(const float* __restrict__ in, unsigned short* __restrict__ out,
                                int n4) {
  int idx = blockIdx.x * 256 + threadIdx.x;
  if (idx >= n4) return;
  float4 v = ((const float4*)in)[idx];
  ushort4 o;
  o.x = bfbits(v.x); o.y = bfbits(v.y); o.z = bfbits(v.z); o.w = bfbits(v.w);
  ((ushort4*)out)[idx] = o;
}

// ---------------- transpose (B,C,T) -> (B,T,C) ----------------
__global__ __launch_bounds__(256) void transpose_fwd(const float* __restrict__ in,
                                                     float* __restrict__ out) {
  __shared__ float tile[32][33];
  int tx = threadIdx.x, ty = threadIdx.y;
  int t0 = blockIdx.x * 32, c0 = blockIdx.y * 32, b = blockIdx.z;
#pragma unroll
  for (int k = 0; k < 4; k++)
    tile[ty + 8 * k][tx] = in[((size_t)(b * Hc + c0 + ty + 8 * k)) * Tt + t0 + tx];
  __syncthreads();
#pragma unroll
  for (int k = 0; k < 4; k++)
    out[((size_t)(b * Tt + t0 + ty + 8 * k)) * Hc + c0 + tx] = tile[tx][ty + 8 * k];
}

// ---------------- transpose (B,T,C) -> (B,C,T) with mask ----------------
__global__ __launch_bounds__(256) void transpose_bwd(const float* __restrict__ in,
                                                     const float* __restrict__ mask,
                                                     float* __restrict__ out) {
  __shared__ float tile[32][33];
  int tx = threadIdx.x, ty = threadIdx.y;
  int t0 = blockIdx.x * 32, c0 = blockIdx.y * 32, b = blockIdx.z;
#pragma unroll
  for (int k = 0; k < 4; k++)
    tile[ty + 8 * k][tx] = in[((size_t)(b * Tt + t0 + ty + 8 * k)) * Hc + c0 + tx];
  __syncthreads();
  float mv = mask[(size_t)b * Tt + t0 + tx];
#pragma unroll
  for (int k = 0; k < 4; k++)
    out[((size_t)(b * Hc + c0 + ty + 8 * k)) * Tt + t0 + tx] = tile[tx][ty + 8 * k] * mv;
}

// ---------------- scan phase 1: chunk-local states ----------------
// lane pair (h, half): each thread handles 16 of the 32 modes -> params fit in VGPRs
__global__ __launch_bounds__(256) void scan_local_t(
    const float* __restrict__ xT, const float* __restrict__ mask,
    const float* __restrict__ wre, const float* __restrict__ wim,
    float* __restrict__ states) {
  int tid = threadIdx.x;
  int h2 = tid >> 1, half = tid & 1;
  int hg = blockIdx.y * 128 + h2;
  int c = blockIdx.x, b = blockIdx.z;
  int nb = half * 16;
  float wr[16], wi[16], sr[16], si[16];
#pragma unroll
  for (int n = 0; n < 16; n++) {
    wr[n] = wre[hg * N2 + nb + n]; wi[n] = wim[hg * N2 + nb + n];
    sr[n] = 0.f; si[n] = 0.f;
  }
  const float* xp = xT + ((size_t)(b * Tt + c * CHUNK)) * Hc + hg;
  const float* mp = mask + (size_t)b * Tt + c * CHUNK;
#pragma unroll 4
  for (int t = 0; t < CHUNK; t++) {
    float u = xp[(size_t)t * Hc] * mp[t];
#pragma unroll
    for (int n = 0; n < 16; n++) {
      float s0 = sr[n];
      sr[n] = fmaf(wr[n], s0, fmaf(-wi[n], si[n], u));
      si[n] = fmaf(wr[n], si[n], wi[n] * s0);
    }
  }
  float* sp = states + (((size_t)(b * Hc + hg)) * NCH + c) * (2 * N2) + 2 * nb;
#pragma unroll
  for (int n = 0; n < 16; n++) { sp[2 * n] = sr[n]; sp[2 * n + 1] = si[n]; }
}

// ---------------- scan phase 2: prefix over chunks, thread per (b,h,n) ----------------
__global__ __launch_bounds__(256) void scan_prefix(
    float* __restrict__ states,
    const float* __restrict__ wSre, const float* __restrict__ wSim) {
  int tid = blockIdx.x * 256 + threadIdx.x;  // (b*Hc + h)*N2 + n
  if (tid >= Bq * Hc * N2) return;
  int n = tid & (N2 - 1);
  int h = (tid >> 5) % Hc;
  int row = tid >> 5;  // b*Hc + h
  float wr = wSre[h * N2 + n], wi = wSim[h * N2 + n];
  float cr = 0.f, ci = 0.f;
  float* base = states + (size_t)row * NCH * 2 * N2 + 2 * n;
  for (int c = 0; c < NCH; c++) {
    float2 s = *(float2*)(base + (size_t)c * 2 * N2);
    *(float2*)(base + (size_t)c * 2 * N2) = make_float2(cr, ci);
    float c0 = cr;
    cr = fmaf(wr, c0, fmaf(-wi, ci, s.x));
    ci = fmaf(wr, ci, fmaf(wi, c0, s.y));
  }
}

// ---------------- scan phase 3: y = gelu(ssm + D*x), bf16 out, pair-split modes ----------------
__global__ __launch_bounds__(256) void scan_out_t(
    const float* __restrict__ xT, const float* __restrict__ mask,
    const float* __restrict__ wre, const float* __restrict__ wim,
    const float* __restrict__ cdre, const float* __restrict__ cdim,
    const float* __restrict__ Dv, const float* __restrict__ states,
    unsigned short* __restrict__ ybf) {
  int tid = threadIdx.x;
  int h2 = tid >> 1, half = tid & 1;
  int hg = blockIdx.y * 128 + h2;
  int c = blockIdx.x, b = blockIdx.z;
  int nb = half * 16;
  float wr[16], wi[16], cdr[16], cdi[16], sr[16], si[16];
  const float* sp = states + (((size_t)(b * Hc + hg)) * NCH + c) * (2 * N2) + 2 * nb;
#pragma unroll
  for (int n = 0; n < 16; n++) {
    wr[n] = wre[hg * N2 + nb + n];  wi[n] = wim[hg * N2 + nb + n];
    cdr[n] = cdre[hg * N2 + nb + n]; cdi[n] = cdim[hg * N2 + nb + n];
    sr[n] = sp[2 * n]; si[n] = sp[2 * n + 1];
  }
  float d = Dv[hg];
  const float* xp = xT + ((size_t)(b * Tt + c * CHUNK)) * Hc + hg;
  const float* mp = mask + (size_t)b * Tt + c * CHUNK;
  unsigned short* yp = ybf + ((size_t)(b * Tt + c * CHUNK)) * Hc + hg;
#pragma unroll 2
  for (int t = 0; t < CHUNK; t++) {
    float u = xp[(size_t)t * Hc] * mp[t];
    float acc = 0.f;
#pragma unroll
    for (int n = 0; n < 16; n++) {
      float s0 = sr[n];
      sr[n] = fmaf(wr[n], s0, fmaf(-wi[n], si[n], u));
      si[n] = fmaf(wr[n], si[n], wi[n] * s0);
      acc = fmaf(cdr[n], sr[n], fmaf(-cdi[n], si[n], acc));
    }
    float accT = acc + __shfl_xor(acc, 1);
    if (half == 0) {
      float v = fmaf(d, u, accT);
      v = 0.5f * v * (1.0f + erff(v * 0.70710678118654752f));
      yp[(size_t)t * Hc] = bfbits(v);
    }
  }
}

// ---------------- MFMA GEMM: out(B,T,N) = act(B,T,K) x W(N,K)^T ----------------
// EPI 0: outf = acc + bias                (fp32)
// EPI 1: outb = relu(acc + bias) * mask   (bf16)
// EPI 2: GLU: W has 2N rows; outf = (a+ba)*sigmoid(g+bg)  (fp32)
template <int EPI>
__global__ __launch_bounds__(256) void mfma_gemm(
    const __bf16* __restrict__ act, const __bf16* __restrict__ W,
    const float* __restrict__ bias, const float* __restrict__ mask,
    float* __restrict__ outf, unsigned short* __restrict__ outb,
    int K, int NOUT) {
  __shared__ __bf16 As[128][32];
  __shared__ __bf16 Bs[128][32];
  __shared__ __bf16 Bs2[(EPI == 2) ? 128 : 1][32];
  int tid = threadIdx.x;
  int b = blockIdx.z;
  int t0 = blockIdx.x * 128, n0 = blockIdx.y * 128;
  int wave = tid >> 6, lane = tid & 63, l16 = lane & 15, quad = lane >> 4;
  int wm = wave >> 1, wn = wave & 1;
  int sr = tid >> 2, sk = (tid & 3) * 8;

  floatx4 acc[4][4];
  floatx4 accg[(EPI == 2) ? 4 : 1][4];
#pragma unroll
  for (int i = 0; i < 4; i++)
#pragma unroll
    for (int j = 0; j < 4; j++) {
      acc[i][j] = (floatx4){0.f, 0.f, 0.f, 0.f};
      if constexpr (EPI == 2) accg[i][j] = (floatx4){0.f, 0.f, 0.f, 0.f};
    }

  const __bf16* aPtr = act + ((size_t)(b * Tt + t0 + sr)) * K + sk;
  const __bf16* bPtr = W + (size_t)(n0 + sr) * K + sk;
  const __bf16* gPtr = (EPI == 2) ? (W + (size_t)(NOUT + n0 + sr) * K + sk) : bPtr;

  for (int k0 = 0; k0 < K; k0 += 32) {
    uint4 a0 = *(const uint4*)(aPtr + k0);
    uint4 a1 = *(const uint4*)(aPtr + k0 + (size_t)64 * K);
    uint4 w0 = *(const uint4*)(bPtr + k0);
    uint4 w1 = *(const uint4*)(bPtr + k0 + (size_t)64 * K);
    uint4 g0, g1;
    if constexpr (EPI == 2) {
      g0 = *(const uint4*)(gPtr + k0);
      g1 = *(const uint4*)(gPtr + k0 + (size_t)64 * K);
    }
    __syncthreads();
    *(uint4*)&As[sr][sk] = a0; *(uint4*)&As[sr + 64][sk] = a1;
    *(uint4*)&Bs[sr][sk] = w0; *(uint4*)&Bs[sr + 64][sk] = w1;
    if constexpr (EPI == 2) { *(uint4*)&Bs2[sr][sk] = g0; *(uint4*)&Bs2[sr + 64][sk] = g1; }
    __syncthreads();
    bf16x8 af[4], bfr[4], gfr[(EPI == 2) ? 4 : 1];
#pragma unroll
    for (int i = 0; i < 4; i++)
      af[i] = *(const bf16x8*)&As[wm * 64 + i * 16 + l16][quad * 8];
#pragma unroll
    for (int j = 0; j < 4; j++) {
      bfr[j] = *(const bf16x8*)&Bs[wn * 64 + j * 16 + l16][quad * 8];
      if constexpr (EPI == 2)
        gfr[j] = *(const bf16x8*)&Bs2[wn * 64 + j * 16 + l16][quad * 8];
    }
#pragma unroll
    for (int i = 0; i < 4; i++)
#pragma unroll
      for (int j = 0; j < 4; j++) {
        acc[i][j] = __builtin_amdgcn_mfma_f32_16x16x32_bf16(af[i], bfr[j], acc[i][j], 0, 0, 0);
        if constexpr (EPI == 2)
          accg[i][j] = __builtin_amdgcn_mfma_f32_16x16x32_bf16(af[i], gfr[j], accg[i][j], 0, 0, 0);
      }
  }

  // epilogue: D row = t (i*16 + quad*4 + r), col = n (j*16 + l16)
#pragma unroll
  for (int i = 0; i < 4; i++) {
    int tb = t0 + wm * 64 + i * 16 + quad * 4;
    float mv[4];
    if constexpr (EPI == 1) {
#pragma unroll
      for (int r = 0; r < 4; r++) mv[r] = mask[(size_t)b * Tt + tb + r];
    }
#pragma unroll
    for (int j = 0; j < 4; j++) {
      int n = n0 + wn * 64 + j * 16 + l16;
      float bn = bias[n];
      float bg = (EPI == 2) ? bias[NOUT + n] : 0.f;
#pragma unroll
      for (int r = 0; r < 4; r++) {
        size_t o = ((size_t)(b * Tt + tb + r)) * NOUT + n;
        if constexpr (EPI == 0) {
          outf[o] = acc[i][j][r] + bn;
        } else if constexpr (EPI == 1) {
          float v = fmaxf(acc[i][j][r] + bn, 0.f) * mv[r];
          outb[o] = bfbits(v);
        } else {
          float a = acc[i][j][r] + bn;
          float g = accg[i][j][r] + bg;
          outf[o] = a / (1.f + expf(-g));
        }
      }
    }
  }
}

// ---------------- LayerNorm over C (contiguous), wave per row ----------------
__global__ __launch_bounds__(256) void ln_t(
    const float* __restrict__ in1, const float* __restrict__ in2,
    const float* __restrict__ mask, const float* __restrict__ gamma,
    const float* __restrict__ beta, float* __restrict__ out,
    unsigned short* __restrict__ outb, int m1, int m2) {
  int row = blockIdx.x * 4 + (threadIdx.x >> 6);  // b*Tt + t
  int lane = threadIdx.x & 63;
  float mv = mask[row];
  float f1 = m1 ? mv : 1.f;
  float f2 = m2 ? mv : 1.f;
  size_t base = (size_t)row * Hc;
  float v[6], sum = 0.f, sq = 0.f;
#pragma unroll
  for (int j = 0; j < 6; j++) {
    int idx = lane + 64 * j;
    float a = in1[base + idx] * f1 + in2[base + idx] * f2;
    v[j] = a; sum += a; sq = fmaf(a, a, sq);
  }
#pragma unroll
  for (int off = 32; off >= 1; off >>= 1) {
    sum += __shfl_xor(sum, off, 64);
    sq  += __shfl_xor(sq,  off, 64);
  }
  float m = sum * (1.f / Hc);
  float var = sq * (1.f / Hc) - m * m;
  float rs = rsqrtf(var + 1e-4f);
#pragma unroll
  for (int j = 0; j < 6; j++) {
    int idx = lane + 64 * j;
    float o = (v[j] - m) * rs * gamma[idx] + beta[idx];
    out[base + idx] = o;
    if (outb) outb[base + idx] = bfbits(o * mv);
  }
}

// ---------------- diagnostic ----------------
__global__ void diag_kernel(float* out, float v) {
  if (blockIdx.x == 0 && threadIdx.x == 0) out[0] = v;
}

extern "C" void kernel_launch(void* const* d_in, const int* in_sizes, int n_in,
                              void* d_out, int out_size, void* d_ws, size_t ws_size,
                              hipStream_t stream) {
  const float* x_in  = (const float*)d_in[0];
  const float* xmask = (const float*)d_in[1];
  const float* log_dt = (const float*)d_in[2];
  const float* A_re = (const float*)d_in[3];
  const float* A_im = (const float*)d_in[4];
  const float* C_re = (const float*)d_in[5];
  const float* C_im = (const float*)d_in[6];
  const float* Dv   = (const float*)d_in[7];
  const float* Wout = (const float*)d_in[8];
  const float* bout = (const float*)d_in[9];
  const float* g1   = (const float*)d_in[10];
  const float* be1  = (const float*)d_in[11];
  const float* W1   = (const float*)d_in[12];
  const float* bf1  = (const float*)d_in[13];
  const float* W2   = (const float*)d_in[14];
  const float* bf2  = (const float*)d_in[15];
  const float* g2   = (const float*)d_in[16];
  const float* be2  = (const float*)d_in[17];

  const size_t NXf   = (size_t)Bq * Hc * Tt;          // 12,582,912 floats
  const size_t NP    = (size_t)LYR * Hc * N2;         // 73,728
  const size_t YBFf  = NXf / 2;                       // bf16 y / x1b region, in floats
  const size_t HBFf  = (size_t)Bq * Tt * HFq / 2;     // bf16 h region, in floats
  const size_t WOUTf = (size_t)LYR * TWOH * Hc / 2;
  const size_t W1f   = (size_t)LYR * HFq * Hc / 2;
  const size_t W2f   = (size_t)LYR * Hc * HFq / 2;

  size_t need = 2 * NXf + YBFf + HBFf + WOUTf + W1f + W2f + 6 * NP;
  if (ws_size / 4 < need) {
    diag_kernel<<<1, 64, 0, stream>>>((float*)d_out, 1000.0f + (float)(ws_size >> 20));
    return;
  }

  float* ws = (float*)d_ws;
  float* xT   = ws;                       // (B,T,C) fp32 layer state
  float* tmp  = xT + NXf;                 // (B,T,C) fp32: glu out, then ffn2 out
  float* ybfF = tmp + NXf;                // bf16 (B,T,C): y, then x1*mask
  float* hbfF = ybfF + YBFf;              // bf16 (B,T,HF): ffn hidden; scan-states overlay
  float* wobF = hbfF + HBFf;              // bf16 weights
  float* w1bF = wobF + WOUTf;
  float* w2bF = w1bF + W1f;
  float* wre  = w2bF + W2f;
  float* wim  = wre + NP;
  float* cdre = wim + NP;
  float* cdim = cdre + NP;
  float* wSre = cdim + NP;
  float* wSim = wSre + NP;

  unsigned short* ybf = (unsigned short*)ybfF;
  unsigned short* hbf = (unsigned short*)hbfF;
  float* stbuf = hbfF;                    // states overlay (6.3M < 25.2M floats)
  unsigned short* wob = (unsigned short*)wobF;
  unsigned short* w1b = (unsigned short*)w1bF;
  unsigned short* w2b = (unsigned short*)w2bF;
  float* x1 = (float*)d_out;              // (B,T,C) fp32 post-LN1 lives in d_out

  param_kernel<<<(LYR * Hc * N2 + 255) / 256, 256, 0, stream>>>(
      log_dt, A_re, A_im, C_re, C_im, wre, wim, cdre, cdim, wSre, wSim);
  cvt_bf16_kernel<<<(int)(2 * WOUTf + 1023) / 1024, 256, 0, stream>>>(Wout, wob, (int)(WOUTf / 2));
  cvt_bf16_kernel<<<(int)(2 * W1f + 1023) / 1024, 256, 0, stream>>>(W1, w1b, (int)(W1f / 2));
  cvt_bf16_kernel<<<(int)(2 * W2f + 1023) / 1024, 256, 0, stream>>>(W2, w2b, (int)(W2f / 2));
  transpose_fwd<<<dim3(Tt / 32, Hc / 32, Bq), dim3(32, 8), 0, stream>>>(x_in, xT);

  for (int i = 0; i < LYR; i++) {
    size_t po = (size_t)i * Hc * N2;

    scan_local_t<<<dim3(NCH, Hc / 128, Bq), 256, 0, stream>>>(xT, xmask, wre + po, wim + po, stbuf);
    scan_prefix<<<(Bq * Hc * N2) / 256, 256, 0, stream>>>(stbuf, wSre + po, wSim + po);
    scan_out_t<<<dim3(NCH, Hc / 128, Bq), 256, 0, stream>>>(
        xT, xmask, wre + po, wim + po, cdre + po, cdim + po, Dv + (size_t)i * Hc, stbuf, ybf);

    // glu = GLU(Wout*y + bout) -> tmp (fp32)
    mfma_gemm<2><<<dim3(Tt / 128, Hc / 128, Bq), 256, 0, stream>>>(
        (const __bf16*)ybf, (const __bf16*)(wob + (size_t)i * TWOH * Hc),
        bout + (size_t)i * TWOH, xmask, tmp, nullptr, Hc, Hc);

    // x1 = LN(x*mask + glu) -> d_out fp32 ; x1b = bf16(x1*mask) -> ybf
    ln_t<<<(Bq * Tt) / 4, 256, 0, stream>>>(
        xT, tmp, xmask, g1 + (size_t)i * Hc, be1 + (size_t)i * Hc, x1, ybf, 1, 0);

    // h = bf16(relu(W1*x1b + bf1) * mask) -> hbf
    mfma_gemm<1><<<dim3(Tt / 128, HFq / 128, Bq), 256, 0, stream>>>(
        (const __bf16*)ybf, (const __bf16*)(w1b + (size_t)i * HFq * Hc),
        bf1 + (size_t)i * HFq, xmask, nullptr, hbf, Hc, HFq);

    // f = W2*h + bf2 -> tmp (fp32)
    mfma_gemm<0><<<dim3(Tt / 128, Hc / 128, Bq), 256, 0, stream>>>(
        (const __bf16*)hbf, (const __bf16*)(w2b + (size_t)i * Hc * HFq),
        bf2 + (size_t)i * Hc, xmask, tmp, nullptr, HFq, Hc);

    // x = LN(x1 + f*mask) -> xT
    ln_t<<<(Bq * Tt) / 4, 256, 0, stream>>>(
        x1, tmp, xmask, g2 + (size_t)i * Hc, be2 + (size_t)i * Hc, xT, nullptr, 0, 1);
  }

  transpose_bwd<<<dim3(Tt / 32, Hc / 32, Bq), dim3(32, 8), 0, stream>>>(xT, xmask, (float*)d_out);
}